// Round 8
// baseline (45.747 us; speedup 1.0000x reference)
//
#include <hip/hip_runtime.h>
#include <hip/hip_cooperative_groups.h>

namespace cg = cooperative_groups;

#define HH 96
#define WW 96
#define NPX (HH*WW)         // 9216
#define HID 16
#define OUTC 10
#define TT 8
#define BB 2
#define BETA 0.9f

#define THREADS 384         // 6 waves; thread = (col 0..95) x (cg 0..3)
#define NBLK (BB*HH)        // 192

// ws layout:
//  u32   [0 .. 6144)        : packed count partials, wsu[(t*4+cg)*NBLK + blk],
//                             byte j = count for channel d = cg*4+j  (<=96)
//  float [6144 .. 6336)     : smooth partials, ws[SM_BASE + blk]
#define SM_BASE (TT*4*NBLK)          // 6144
#define DENOM 2359296.0f             // T*B*N*HID

#define SLABW 292        // padded words per (t,g) x-slab (73 float4)
#define VPAD 97          // vbuf row stride in float4

// z (no bias): project 3 input channels to this thread's 4 hid channels
__device__ __forceinline__ float4 proj4(float xa, float xb, float xc,
                                        const float* w0, const float* w1, const float* w2)
{
  float4 r;
  r.x = fmaf(xc, w2[0], fmaf(xb, w1[0], xa*w0[0]));
  r.y = fmaf(xc, w2[1], fmaf(xb, w1[1], xa*w0[1]));
  r.z = fmaf(xc, w2[2], fmaf(xb, w1[2], xa*w0[2]));
  r.w = fmaf(xc, w2[3], fmaf(xb, w1[3], xa*w0[3]));
  return r;
}

__global__ __launch_bounds__(THREADS)
void snn_coop(const float* __restrict__ x,
              const float* __restrict__ wproj,
              const float* __restrict__ bproj,
              const float* __restrict__ whead,
              const float* __restrict__ bhead,
              float* __restrict__ ws,
              float* __restrict__ out)
{
  __shared__ float4 xraw4[24*73];        // 28032 B: raw x, slab s = t*3+g, stride 73
  __shared__ float4 vbuf[TT*VPAD];       // 12416 B: vertical x 3-sums, [t*97 + col]
  __shared__ unsigned cslot[TT][6][4];   // 768 B: per-t per-wave packed counts
  __shared__ float  smslot[6];
  __shared__ float  cnt_s[TT][BB][HID];  // finalize stage (block 0 only)

  const int row  = blockIdx.x;    // 0..95
  const int b    = blockIdx.y;    // 0..1
  const int blk  = b*HH + row;
  const int tid  = threadIdx.x;
  const int lane = tid & 63;
  const int wv   = tid >> 6;      // 0..5
  const int cg   = tid & 3;       // channel group (4 hid channels)
  const int col  = tid >> 2;      // 0..95

  // per-thread projection weights for this channel group
  float w0[4], w1[4], w2[4], bp[4];
#pragma unroll
  for (int j = 0; j < 4; ++j) {
    w0[j] = wproj[0*HID + cg*4 + j];
    w1[j] = wproj[1*HID + cg*4 + j];
    w2[j] = wproj[2*HID + cg*4 + j];
    bp[j] = bproj[cg*4 + j];
  }

  // ---- prologue: coalesced float4 copy of the whole x slab into LDS ----
#pragma unroll
  for (int i = 0; i < 5; ++i) {
    int idx = tid + THREADS*i;          // 0..1919
    if (idx < 1728) {
      int s = idx / 72;                 // slab = t*3 + g
      int q = idx - s*72;
      int t = s / 3;
      int g = s - t*3;
      int rr = row + g - 1;
      rr = (rr < 0) ? rr + HH : (rr >= HH ? rr - HH : rr);
      const float4* src = (const float4*)(x + ((size_t)(t*BB + b)*NPX + (size_t)rr*WW)*3);
      xraw4[s*73 + q] = src[q];
    }
  }
  __syncthreads();
  const float* xr = (const float*)xraw4;

  // ---- phase A: vertical x 3-sums for ALL 8 t (each thread does 2 t's) ----
#pragma unroll
  for (int i = 0; i < 2; ++i) {
    int t = cg*2 + i;
    int base = t*3*SLABW + col*3;
    float s0 = xr[base    ] + xr[base + SLABW    ] + xr[base + 2*SLABW    ];
    float s1 = xr[base + 1] + xr[base + SLABW + 1] + xr[base + 2*SLABW + 1];
    float s2 = xr[base + 2] + xr[base + SLABW + 2] + xr[base + 2*SLABW + 2];
    vbuf[t*VPAD + col] = make_float4(s0, s1, s2, 0.f);
  }
  __syncthreads();

  // ---- phase B: box9 -> project -> LIF scan; ballot spike counting ----
  const int cl = (col == 0)    ? (WW-1) : (col-1);
  const int cr = (col == WW-1) ? 0      : (col+1);
  float4 v = make_float4(0.f, 0.f, 0.f, 0.f);
  float sm = 0.f;
  unsigned packw[TT];
  const float inv9 = 1.0f/9.0f;
  const unsigned long long fm = 0x1111111111111111ULL << cg;  // lanes with lane%4==cg

#pragma unroll
  for (int t = 0; t < TT; ++t) {
    float4 a0 = vbuf[t*VPAD + cl];
    float4 a1 = vbuf[t*VPAD + col];
    float4 a2 = vbuf[t*VPAD + cr];
    float bx = a0.x + a1.x + a2.x;
    float by = a0.y + a1.y + a2.y;
    float bz = a0.z + a1.z + a2.z;
    int cb = (t*3 + 1)*SLABW + col*3;
    float xc0 = xr[cb], xc1 = xr[cb+1], xc2 = xr[cb+2];
    float4 pb = proj4(bx, by, bz, w0, w1, w2);
    float4 pz = proj4(xc0, xc1, xc2, w0, w1, w2);
    float ax = pb.x*inv9, ay = pb.y*inv9, az = pb.z*inv9, aw = pb.w*inv9;
    sm += fabsf(ax - pz.x) + fabsf(ay - pz.y) + fabsf(az - pz.z) + fabsf(aw - pz.w);
    float vx = fmaf(BETA, v.x, ax + bp[0]);
    float vy = fmaf(BETA, v.y, ay + bp[1]);
    float vz = fmaf(BETA, v.z, az + bp[2]);
    float vw = fmaf(BETA, v.w, aw + bp[3]);
    bool b0 = vx > 1.0f, b1 = vy > 1.0f, b2 = vz > 1.0f, b3 = vw > 1.0f;
    unsigned long long m0 = __ballot(b0);
    unsigned long long m1 = __ballot(b1);
    unsigned long long m2 = __ballot(b2);
    unsigned long long m3 = __ballot(b3);
    unsigned c0 = (unsigned)__popcll(m0 & fm);
    unsigned c1 = (unsigned)__popcll(m1 & fm);
    unsigned c2 = (unsigned)__popcll(m2 & fm);
    unsigned c3 = (unsigned)__popcll(m3 & fm);
    packw[t] = c0 | (c1 << 8) | (c2 << 16) | (c3 << 24);
    v.x = vx - (b0 ? 1.0f : 0.0f);
    v.y = vy - (b1 ? 1.0f : 0.0f);
    v.z = vz - (b2 ? 1.0f : 0.0f);
    v.w = vw - (b3 ? 1.0f : 0.0f);
  }

  // ---- per-block epilogue: publish partials ----
  if (lane < 4) {                 // lane == cg for lanes 0..3
#pragma unroll
    for (int t = 0; t < TT; ++t)
      cslot[t][wv][lane] = packw[t];
  }
#pragma unroll
  for (int off = 1; off < 64; off <<= 1)
    sm += __shfl_xor(sm, off);
  if (lane == 0) smslot[wv] = sm;
  __syncthreads();

  unsigned* wsu = (unsigned*)ws;
  if (tid < 32) {                 // one (t, cg) each; combine 6 waves (bytewise-safe)
    int t = tid >> 2, c4 = tid & 3;
    unsigned s = cslot[t][0][c4] + cslot[t][1][c4] + cslot[t][2][c4]
               + cslot[t][3][c4] + cslot[t][4][c4] + cslot[t][5][c4];
    wsu[(t*4 + c4)*NBLK + blk] = s;
  }
  if (tid == 0)
    ws[SM_BASE + blk] = smslot[0]+smslot[1]+smslot[2]+smslot[3]+smslot[4]+smslot[5];

  // ---- grid-wide barrier (runtime-initialized; memory-ordering included) ----
  cg::this_grid().sync();

  // ---- finalize: block (0,0) only ----
  if (row != 0 || b != 0) return;

  // smooth threads (256..319): issue global loads immediately (overlaps stage 1)
  float smacc = 0.f;
  if (tid >= 256 && tid < 320) {
    int i = tid - 256;
    smacc = ws[SM_BASE + i] + ws[SM_BASE + 64 + i] + ws[SM_BASE + 128 + i];
  }

  // stage 1 (threads 0..255): 32 slots (t*4+cg) x 8 subs; each sums 24 packed
  // u32 (6 uint4), then quad-reduce over subs via shfl.
  if (tid < 256) {
    int slot = tid >> 3, sub = tid & 7;
    const uint4* src = (const uint4*)((const unsigned*)ws + slot*NBLK) + sub*6;
    unsigned c0 = 0, c1 = 0, c2 = 0, c3 = 0;
#pragma unroll
    for (int q = 0; q < 6; ++q) {
      uint4 a = src[q];
      unsigned p0 = a.x + a.y, p1 = a.z + a.w;   // bytes <=96, pair-sum <=192: safe
      c0 += (p0 & 0xffu)        + (p1 & 0xffu);
      c1 += ((p0 >> 8) & 0xffu) + ((p1 >> 8) & 0xffu);
      c2 += ((p0 >> 16) & 0xffu)+ ((p1 >> 16) & 0xffu);
      c3 += (p0 >> 24)          + (p1 >> 24);
    }
    c0 += __shfl_xor(c0, 1); c1 += __shfl_xor(c1, 1);
    c2 += __shfl_xor(c2, 1); c3 += __shfl_xor(c3, 1);
    c0 += __shfl_xor(c0, 2); c1 += __shfl_xor(c1, 2);
    c2 += __shfl_xor(c2, 2); c3 += __shfl_xor(c3, 2);
    if ((sub & 3) == 0) {
      int half = sub >> 2;                // 0 -> batch 0, 1 -> batch 1
      int t = slot >> 2, c4 = slot & 3;
      cnt_s[t][half][c4*4 + 0] = (float)c0;
      cnt_s[t][half][c4*4 + 1] = (float)c1;
      cnt_s[t][half][c4*4 + 2] = (float)c2;
      cnt_s[t][half][c4*4 + 3] = (float)c3;
    }
  }
  __syncthreads();    // all 384 threads of block 0 reach this

  if (tid < 160) {
    // logits_seq: out[20 + (t,b,o)]
    int t  = tid / (BB*OUTC);
    int r  = tid - t*(BB*OUTC);
    int bq = r / OUTC;
    int o  = r - bq*OUTC;
    float acc = bhead[o];
#pragma unroll
    for (int d = 0; d < HID; ++d)
      acc = fmaf(cnt_s[t][bq][d] * (1.0f/9216.0f), whead[d*OUTC + o], acc);
    out[20 + tid] = acc;
  } else if (tid < 180) {
    // time-mean readout, independent of logits threads
    int r  = tid - 160;
    int bq = r / OUTC;
    int o  = r - bq*OUTC;
    float acc = bhead[o];
#pragma unroll
    for (int d = 0; d < HID; ++d) {
      float s = 0.f;
#pragma unroll
      for (int t = 0; t < TT; ++t) s += cnt_s[t][bq][d];
      acc = fmaf(s * (1.0f/(9216.0f*TT)), whead[d*OUTC + o], acc);
    }
    out[r] = acc;
  } else if (tid >= 192 && tid < 256) {
    // sr: one wave reduces all 256 counts (exact integers in fp32, any order)
    int i = tid - 192;
    const float* cf = &cnt_s[0][0][0];
    float s = cf[i] + cf[i + 64] + cf[i + 128] + cf[i + 192];
#pragma unroll
    for (int off = 1; off < 64; off <<= 1)
      s += __shfl_xor(s, off);
    if (i == 0) out[180] = s / DENOM;
  } else if (tid >= 256 && tid < 320) {
    // smooth: butterfly on the preloaded partial sums
#pragma unroll
    for (int off = 1; off < 64; off <<= 1)
      smacc += __shfl_xor(smacc, off);
    if (tid == 256) out[181] = smacc / DENOM;
  }
}

extern "C" void kernel_launch(void* const* d_in, const int* in_sizes, int n_in,
                              void* d_out, int out_size, void* d_ws, size_t ws_size,
                              hipStream_t stream)
{
  const float* x     = (const float*)d_in[0];
  const float* wproj = (const float*)d_in[1];
  const float* bproj = (const float*)d_in[2];
  const float* whead = (const float*)d_in[3];
  const float* bhead = (const float*)d_in[4];
  float* out = (float*)d_out;
  float* ws  = (float*)d_ws;

  void* args[] = { (void*)&x, (void*)&wproj, (void*)&bproj,
                   (void*)&whead, (void*)&bhead, (void*)&ws, (void*)&out };
  dim3 grid(HH, BB), block(THREADS);
  (void)hipLaunchCooperativeKernel((const void*)snn_coop, grid, block, args, 0, stream);
}

// Round 9
// 19.390 us; speedup vs baseline: 2.3592x; 2.3592x over previous
//
#include <hip/hip_runtime.h>

#define HH 96
#define WW 96
#define NPX (HH*WW)         // 9216
#define HID 16
#define OUTC 10
#define TT 8
#define BB 2
#define BETA 0.9f

#define THREADS 384         // 6 waves; thread = (col 0..95) x (cg 0..3)
#define NBLK (BB*HH)        // 192

// ws layout:
//  u32   [0 .. 6144)   : packed count partials, wsu[(t*4+cg)*NBLK + blk],
//                        byte j = count for channel d = cg*4+j  (<=96)
//  float [6144 .. 6336): smooth partials, ws[SM_BASE + blk]
//  u64   [byte 32768)  : 3-word arrival bitmask (init-free rendezvous)
#define SM_BASE (TT*4*NBLK)          // 6144
#define MASKQ 4096                   // u64 index into ws (byte offset 32768)
#define DENOM 2359296.0f             // T*B*N*HID

#define SLABW 292        // padded words per (t,g) x-slab (73 float4)
#define VPAD 97          // vbuf row stride in float4

// z (no bias): project 3 input channels to this thread's 4 hid channels
__device__ __forceinline__ float4 proj4(float xa, float xb, float xc,
                                        const float* w0, const float* w1, const float* w2)
{
  float4 r;
  r.x = fmaf(xc, w2[0], fmaf(xb, w1[0], xa*w0[0]));
  r.y = fmaf(xc, w2[1], fmaf(xb, w1[1], xa*w0[1]));
  r.z = fmaf(xc, w2[2], fmaf(xb, w1[2], xa*w0[2]));
  r.w = fmaf(xc, w2[3], fmaf(xb, w1[3], xa*w0[3]));
  return r;
}

__global__ __launch_bounds__(THREADS)
void snn_one(const float* __restrict__ x,
             const float* __restrict__ wproj,
             const float* __restrict__ bproj,
             const float* __restrict__ whead,
             const float* __restrict__ bhead,
             float* __restrict__ ws,
             float* __restrict__ out)
{
  __shared__ float4 xraw4[24*73];        // 28032 B
  __shared__ float4 vbuf[TT*VPAD];       // 12416 B
  __shared__ unsigned cslot[TT][6][4];   // 768 B
  __shared__ float  smslot[6];
  __shared__ float  cnt_s[TT][BB][HID];  // finalize stage (completer block only)
  __shared__ int    lastflag;

  const int row  = blockIdx.x;    // 0..95
  const int b    = blockIdx.y;    // 0..1
  const int blk  = b*HH + row;
  const int tid  = threadIdx.x;
  const int lane = tid & 63;
  const int wv   = tid >> 6;      // 0..5
  const int cg   = tid & 3;       // channel group (4 hid channels)
  const int col  = tid >> 2;      // 0..95

  // per-thread projection weights for this channel group
  float w0[4], w1[4], w2[4], bp[4];
#pragma unroll
  for (int j = 0; j < 4; ++j) {
    w0[j] = wproj[0*HID + cg*4 + j];
    w1[j] = wproj[1*HID + cg*4 + j];
    w2[j] = wproj[2*HID + cg*4 + j];
    bp[j] = bproj[cg*4 + j];
  }

  // ---- prologue: coalesced float4 copy of the whole x slab into LDS ----
#pragma unroll
  for (int i = 0; i < 5; ++i) {
    int idx = tid + THREADS*i;          // 0..1919
    if (idx < 1728) {
      int s = idx / 72;                 // slab = t*3 + g
      int q = idx - s*72;
      int t = s / 3;
      int g = s - t*3;
      int rr = row + g - 1;
      rr = (rr < 0) ? rr + HH : (rr >= HH ? rr - HH : rr);
      const float4* src = (const float4*)(x + ((size_t)(t*BB + b)*NPX + (size_t)rr*WW)*3);
      xraw4[s*73 + q] = src[q];
    }
  }
  __syncthreads();
  const float* xr = (const float*)xraw4;

  // ---- phase A: vertical x 3-sums for ALL 8 t (each thread does 2 t's) ----
#pragma unroll
  for (int i = 0; i < 2; ++i) {
    int t = cg*2 + i;
    int base = t*3*SLABW + col*3;
    float s0 = xr[base    ] + xr[base + SLABW    ] + xr[base + 2*SLABW    ];
    float s1 = xr[base + 1] + xr[base + SLABW + 1] + xr[base + 2*SLABW + 1];
    float s2 = xr[base + 2] + xr[base + SLABW + 2] + xr[base + 2*SLABW + 2];
    vbuf[t*VPAD + col] = make_float4(s0, s1, s2, 0.f);
  }
  __syncthreads();

  // ---- phase B: box9 -> project -> LIF scan; ballot spike counting ----
  const int cl = (col == 0)    ? (WW-1) : (col-1);
  const int cr = (col == WW-1) ? 0      : (col+1);
  float4 v = make_float4(0.f, 0.f, 0.f, 0.f);
  float sm = 0.f;
  unsigned packw[TT];
  const float inv9 = 1.0f/9.0f;
  const unsigned long long fm = 0x1111111111111111ULL << cg;  // lanes with lane%4==cg

#pragma unroll
  for (int t = 0; t < TT; ++t) {
    float4 a0 = vbuf[t*VPAD + cl];
    float4 a1 = vbuf[t*VPAD + col];
    float4 a2 = vbuf[t*VPAD + cr];
    float bx = a0.x + a1.x + a2.x;
    float by = a0.y + a1.y + a2.y;
    float bz = a0.z + a1.z + a2.z;
    int cb = (t*3 + 1)*SLABW + col*3;
    float xc0 = xr[cb], xc1 = xr[cb+1], xc2 = xr[cb+2];
    float4 pb = proj4(bx, by, bz, w0, w1, w2);
    float4 pz = proj4(xc0, xc1, xc2, w0, w1, w2);
    float ax = pb.x*inv9, ay = pb.y*inv9, az = pb.z*inv9, aw = pb.w*inv9;
    sm += fabsf(ax - pz.x) + fabsf(ay - pz.y) + fabsf(az - pz.z) + fabsf(aw - pz.w);
    float vx = fmaf(BETA, v.x, ax + bp[0]);
    float vy = fmaf(BETA, v.y, ay + bp[1]);
    float vz = fmaf(BETA, v.z, az + bp[2]);
    float vw = fmaf(BETA, v.w, aw + bp[3]);
    bool b0 = vx > 1.0f, b1 = vy > 1.0f, b2 = vz > 1.0f, b3 = vw > 1.0f;
    unsigned long long m0 = __ballot(b0);
    unsigned long long m1 = __ballot(b1);
    unsigned long long m2 = __ballot(b2);
    unsigned long long m3 = __ballot(b3);
    unsigned c0 = (unsigned)__popcll(m0 & fm);
    unsigned c1 = (unsigned)__popcll(m1 & fm);
    unsigned c2 = (unsigned)__popcll(m2 & fm);
    unsigned c3 = (unsigned)__popcll(m3 & fm);
    packw[t] = c0 | (c1 << 8) | (c2 << 16) | (c3 << 24);
    v.x = vx - (b0 ? 1.0f : 0.0f);
    v.y = vy - (b1 ? 1.0f : 0.0f);
    v.z = vz - (b2 ? 1.0f : 0.0f);
    v.w = vw - (b3 ? 1.0f : 0.0f);
  }

  // ---- per-block epilogue: publish partials ----
  if (lane < 4) {                 // lane == cg for lanes 0..3
#pragma unroll
    for (int t = 0; t < TT; ++t)
      cslot[t][wv][lane] = packw[t];
  }
#pragma unroll
  for (int off = 1; off < 64; off <<= 1)
    sm += __shfl_xor(sm, off);
  if (lane == 0) smslot[wv] = sm;
  __syncthreads();

  unsigned* wsu = (unsigned*)ws;
  if (tid < 32) {                 // one (t, cg) each; combine 6 waves (bytewise-safe)
    int t = tid >> 2, c4 = tid & 3;
    unsigned s = cslot[t][0][c4] + cslot[t][1][c4] + cslot[t][2][c4]
               + cslot[t][3][c4] + cslot[t][4][c4] + cslot[t][5][c4];
    wsu[(t*4 + c4)*NBLK + blk] = s;
  }
  if (tid == 0)
    ws[SM_BASE + blk] = smslot[0]+smslot[1]+smslot[2]+smslot[3]+smslot[4]+smslot[5];

  // ---- init-free rendezvous: 192-bit arrival mask ----
  __syncthreads();                // all publish stores drained (vmcnt 0 per wave)
  if (tid == 0) {
    __threadfence();              // release: write back local caches device-wide
    unsigned long long* msk = (unsigned long long*)ws + MASKQ;
    int w = blk >> 6;
    unsigned long long bit = 1ull << (blk & 63);
    unsigned long long old = atomicOr(&msk[w], bit);
    bool full = ((old | bit) == ~0ull);
    if (full) {
#pragma unroll
      for (int q = 0; q < 3; ++q)
        if (q != w) full = full && (atomicOr(&msk[q], 0ull) == ~0ull);
    }
    if (full) {                   // completer: reset mask for the next call
      atomicAnd(&msk[0], 0ull);
      atomicAnd(&msk[1], 0ull);
      atomicAnd(&msk[2], 0ull);
    }
    lastflag = full ? 1 : 0;
  }
  __syncthreads();
  if (!lastflag) return;
  __threadfence();                // acquire: invalidate caches before reading partials

  // ---- finalize (completer block only) ----
  // smooth threads (256..319): issue global loads immediately (overlap stage 1)
  float smacc = 0.f;
  if (tid >= 256 && tid < 320) {
    int i = tid - 256;
    smacc = ws[SM_BASE + i] + ws[SM_BASE + 64 + i] + ws[SM_BASE + 128 + i];
  }

  // stage 1 (threads 0..255): 32 slots (t*4+cg) x 8 subs; each sums 24 packed
  // u32 (6 uint4), then quad-reduce over subs via shfl.
  if (tid < 256) {
    int slot = tid >> 3, sub = tid & 7;
    const uint4* src = (const uint4*)((const unsigned*)ws + slot*NBLK) + sub*6;
    unsigned c0 = 0, c1 = 0, c2 = 0, c3 = 0;
#pragma unroll
    for (int q = 0; q < 6; ++q) {
      uint4 a = src[q];
      unsigned p0 = a.x + a.y, p1 = a.z + a.w;   // bytes <=96, pair-sum <=192: safe
      c0 += (p0 & 0xffu)        + (p1 & 0xffu);
      c1 += ((p0 >> 8) & 0xffu) + ((p1 >> 8) & 0xffu);
      c2 += ((p0 >> 16) & 0xffu)+ ((p1 >> 16) & 0xffu);
      c3 += (p0 >> 24)          + (p1 >> 24);
    }
    c0 += __shfl_xor(c0, 1); c1 += __shfl_xor(c1, 1);
    c2 += __shfl_xor(c2, 1); c3 += __shfl_xor(c3, 1);
    c0 += __shfl_xor(c0, 2); c1 += __shfl_xor(c1, 2);
    c2 += __shfl_xor(c2, 2); c3 += __shfl_xor(c3, 2);
    if ((sub & 3) == 0) {
      int half = sub >> 2;                // 0 -> batch 0, 1 -> batch 1
      int t = slot >> 2, c4 = slot & 3;
      cnt_s[t][half][c4*4 + 0] = (float)c0;
      cnt_s[t][half][c4*4 + 1] = (float)c1;
      cnt_s[t][half][c4*4 + 2] = (float)c2;
      cnt_s[t][half][c4*4 + 3] = (float)c3;
    }
  }
  __syncthreads();

  if (tid < 160) {
    // logits_seq: out[20 + (t,b,o)]
    int t  = tid / (BB*OUTC);
    int r  = tid - t*(BB*OUTC);
    int bq = r / OUTC;
    int o  = r - bq*OUTC;
    float acc = bhead[o];
#pragma unroll
    for (int d = 0; d < HID; ++d)
      acc = fmaf(cnt_s[t][bq][d] * (1.0f/9216.0f), whead[d*OUTC + o], acc);
    out[20 + tid] = acc;
  } else if (tid < 180) {
    // time-mean readout, independent of logits threads
    int r  = tid - 160;
    int bq = r / OUTC;
    int o  = r - bq*OUTC;
    float acc = bhead[o];
#pragma unroll
    for (int d = 0; d < HID; ++d) {
      float s = 0.f;
#pragma unroll
      for (int t = 0; t < TT; ++t) s += cnt_s[t][bq][d];
      acc = fmaf(s * (1.0f/(9216.0f*TT)), whead[d*OUTC + o], acc);
    }
    out[r] = acc;
  } else if (tid >= 192 && tid < 256) {
    // sr: one wave reduces all 256 counts (exact integers in fp32, any order)
    int i = tid - 192;
    const float* cf = &cnt_s[0][0][0];
    float s = cf[i] + cf[i + 64] + cf[i + 128] + cf[i + 192];
#pragma unroll
    for (int off = 1; off < 64; off <<= 1)
      s += __shfl_xor(s, off);
    if (i == 0) out[180] = s / DENOM;
  } else if (tid >= 256 && tid < 320) {
    // smooth: butterfly on the preloaded partial sums
#pragma unroll
    for (int off = 1; off < 64; off <<= 1)
      smacc += __shfl_xor(smacc, off);
    if (tid == 256) out[181] = smacc / DENOM;
  }
}

extern "C" void kernel_launch(void* const* d_in, const int* in_sizes, int n_in,
                              void* d_out, int out_size, void* d_ws, size_t ws_size,
                              hipStream_t stream)
{
  const float* x     = (const float*)d_in[0];
  const float* wproj = (const float*)d_in[1];
  const float* bproj = (const float*)d_in[2];
  const float* whead = (const float*)d_in[3];
  const float* bhead = (const float*)d_in[4];
  float* out = (float*)d_out;
  float* ws  = (float*)d_ws;

  dim3 grid(HH, BB);
  snn_one<<<grid, dim3(THREADS), 0, stream>>>(x, wproj, bproj, whead, bhead, ws, out);
}

// Round 10
// 12.753 us; speedup vs baseline: 3.5873x; 1.5205x over previous
//
#include <hip/hip_runtime.h>

#define HH 96
#define WW 96
#define NPX (HH*WW)         // 9216
#define HID 16
#define OUTC 10
#define TT 8
#define BB 2
#define BETA 0.9f

#define THREADS 768         // 12 waves; thread = (col 0..95) x (channel-pair 0..7)
#define NBLK (BB*HH)        // 192

// ws layout (unchanged from round 7):
//  u32   [0 .. 6144)   : packed count partials, wsu[(t*4+cg)*NBLK + blk],
//                        byte j = count for channel d = cg*4+j  (<=96)
//  float [6144 .. 6336): smooth partials, ws[SM_BASE + blk]
#define SM_BASE (TT*4*NBLK)          // 6144
#define DENOM 2359296.0f             // T*B*N*HID

#define SLABW 292        // padded words per (t,g) x-slab (73 float4)
#define VPAD 97          // vbuf row stride in float4

__global__ __launch_bounds__(THREADS)
void snn_main(const float* __restrict__ x,
              const float* __restrict__ wproj,
              const float* __restrict__ bproj,
              float* __restrict__ ws)
{
  __shared__ float4 xraw4[24*73];        // 28032 B: raw x, slab s = t*3+g, stride 73
  __shared__ float4 vbuf[TT*VPAD];       // 12416 B: vertical x 3-sums, [t*97 + col]
  __shared__ unsigned cslot[TT][12][8];  // 3072 B: per-t per-wave packed pair-counts
  __shared__ float  smslot[12];

  const int row  = blockIdx.x;    // 0..95
  const int b    = blockIdx.y;    // 0..1
  const int blk  = b*HH + row;
  const int tid  = threadIdx.x;
  const int lane = tid & 63;
  const int wv   = tid >> 6;      // 0..11
  const int cg2  = tid & 7;       // channel pair (2 hid channels)
  const int col  = tid >> 3;      // 0..95

  // per-thread projection weights for this channel pair
  float w0[2], w1[2], w2[2], bp[2];
#pragma unroll
  for (int j = 0; j < 2; ++j) {
    w0[j] = wproj[0*HID + cg2*2 + j];
    w1[j] = wproj[1*HID + cg2*2 + j];
    w2[j] = wproj[2*HID + cg2*2 + j];
    bp[j] = bproj[cg2*2 + j];
  }

  // ---- prologue: coalesced float4 copy of the whole x slab into LDS ----
#pragma unroll
  for (int i = 0; i < 3; ++i) {
    int idx = tid + THREADS*i;          // 0..2303
    if (idx < 1728) {
      int s = idx / 72;                 // slab = t*3 + g
      int q = idx - s*72;
      int t = s / 3;
      int g = s - t*3;
      int rr = row + g - 1;
      rr = (rr < 0) ? rr + HH : (rr >= HH ? rr - HH : rr);
      const float4* src = (const float4*)(x + ((size_t)(t*BB + b)*NPX + (size_t)rr*WW)*3);
      xraw4[s*73 + q] = src[q];
    }
  }
  __syncthreads();
  const float* xr = (const float*)xraw4;

  // ---- phase A: vertical x 3-sums, one (t, col) slot per thread ----
  {
    int t = tid & 7;                    // note: covers all (t, col) exactly once
    int c = tid >> 3;
    int base = t*3*SLABW + c*3;
    float s0 = xr[base    ] + xr[base + SLABW    ] + xr[base + 2*SLABW    ];
    float s1 = xr[base + 1] + xr[base + SLABW + 1] + xr[base + 2*SLABW + 1];
    float s2 = xr[base + 2] + xr[base + SLABW + 2] + xr[base + 2*SLABW + 2];
    vbuf[t*VPAD + c] = make_float4(s0, s1, s2, 0.f);
  }
  __syncthreads();

  // ---- phase B: box9 -> project -> LIF scan; ballot spike counting ----
  const int cl = (col == 0)    ? (WW-1) : (col-1);
  const int cr = (col == WW-1) ? 0      : (col+1);
  float v0 = 0.f, v1 = 0.f;
  float sm = 0.f;
  unsigned packw[TT];
  const float inv9 = 1.0f/9.0f;
  const unsigned long long fm = 0x0101010101010101ULL << cg2;  // lanes with lane%8==cg2

#pragma unroll
  for (int t = 0; t < TT; ++t) {
    float4 a0 = vbuf[t*VPAD + cl];
    float4 a1 = vbuf[t*VPAD + col];
    float4 a2 = vbuf[t*VPAD + cr];
    float bx = a0.x + a1.x + a2.x;      // box9 sum of x, 3 input channels
    float by = a0.y + a1.y + a2.y;
    float bz = a0.z + a1.z + a2.z;
    int cb = (t*3 + 1)*SLABW + col*3;   // core pixel x
    float xc0 = xr[cb], xc1 = xr[cb+1], xc2 = xr[cb+2];
    float pb0 = fmaf(bz, w2[0], fmaf(by, w1[0], bx*w0[0]));
    float pb1 = fmaf(bz, w2[1], fmaf(by, w1[1], bx*w0[1]));
    float pz0 = fmaf(xc2, w2[0], fmaf(xc1, w1[0], xc0*w0[0]));
    float pz1 = fmaf(xc2, w2[1], fmaf(xc1, w1[1], xc0*w0[1]));
    float ag0 = pb0*inv9, ag1 = pb1*inv9;
    sm += fabsf(ag0 - pz0) + fabsf(ag1 - pz1);
    float vx = fmaf(BETA, v0, ag0 + bp[0]);
    float vy = fmaf(BETA, v1, ag1 + bp[1]);
    bool s0 = vx > 1.0f, s1 = vy > 1.0f;
    unsigned long long m0 = __ballot(s0);
    unsigned long long m1 = __ballot(s1);
    unsigned c0 = (unsigned)__popcll(m0 & fm);   // <=8 (8 cols per wave)
    unsigned c1 = (unsigned)__popcll(m1 & fm);
    packw[t] = c0 | (c1 << 8);
    v0 = vx - (s0 ? 1.0f : 0.0f);
    v1 = vy - (s1 ? 1.0f : 0.0f);
  }

  // ---- per-block epilogue: publish partials ----
  if (lane < 8) {                 // lane == cg2 for lanes 0..7
#pragma unroll
    for (int t = 0; t < TT; ++t)
      cslot[t][wv][lane] = packw[t];
  }
#pragma unroll
  for (int off = 1; off < 64; off <<= 1)
    sm += __shfl_xor(sm, off);
  if (lane == 0) smslot[wv] = sm;
  __syncthreads();

  unsigned* wsu = (unsigned*)ws;
  if (tid < 32) {                 // one (t, cg) each; sum 12 waves, repack 4 bytes
    int t = tid >> 2, c4 = tid & 3;
    unsigned s01 = 0, s23 = 0;    // byte fields: c_even | c_odd<<8, sums <=96: safe
#pragma unroll
    for (int w = 0; w < 12; ++w) {
      s01 += cslot[t][w][c4*2];
      s23 += cslot[t][w][c4*2 + 1];
    }
    wsu[(t*4 + c4)*NBLK + blk] = (s01 & 0xffffu) | ((s23 & 0xffffu) << 16);
  }
  if (tid == 0) {
    float a = 0.f;
#pragma unroll
    for (int w = 0; w < 12; ++w) a += smslot[w];
    ws[SM_BASE + blk] = a;
  }
}

__global__ __launch_bounds__(320)
void snn_final(const float* __restrict__ ws,
               const float* __restrict__ whead,
               const float* __restrict__ bhead,
               float* __restrict__ out)
{
  __shared__ float cnt_s[TT][BB][HID];   // 256 floats
  const int tid  = threadIdx.x;

  // smooth wave (threads 256..319): issue global loads immediately (overlaps stage 1)
  float smacc = 0.f;
  if (tid >= 256) {
    int i = tid - 256;
    smacc = ws[SM_BASE + i] + ws[SM_BASE + 64 + i] + ws[SM_BASE + 128 + i];
  }

  // stage 1 (threads 0..255): 32 slots (t*4+cg) x 8 subs; each sums 24 packed
  // u32 (6 uint4), then quad-reduce over subs via shfl.
  if (tid < 256) {
    const unsigned* wsu = (const unsigned*)ws;
    int slot = tid >> 3, sub = tid & 7;
    const uint4* src = (const uint4*)(wsu + slot*NBLK) + sub*6;
    unsigned c0 = 0, c1 = 0, c2 = 0, c3 = 0;
#pragma unroll
    for (int q = 0; q < 6; ++q) {
      uint4 a = src[q];
      unsigned p0 = a.x + a.y, p1 = a.z + a.w;   // bytes <=96, pair-sum <=192: safe
      c0 += (p0 & 0xffu)        + (p1 & 0xffu);
      c1 += ((p0 >> 8) & 0xffu) + ((p1 >> 8) & 0xffu);
      c2 += ((p0 >> 16) & 0xffu)+ ((p1 >> 16) & 0xffu);
      c3 += (p0 >> 24)          + (p1 >> 24);
    }
    c0 += __shfl_xor(c0, 1); c1 += __shfl_xor(c1, 1);
    c2 += __shfl_xor(c2, 1); c3 += __shfl_xor(c3, 1);
    c0 += __shfl_xor(c0, 2); c1 += __shfl_xor(c1, 2);
    c2 += __shfl_xor(c2, 2); c3 += __shfl_xor(c3, 2);
    if ((sub & 3) == 0) {
      int half = sub >> 2;                // 0 -> batch 0, 1 -> batch 1
      int t = slot >> 2, cg = slot & 3;
      cnt_s[t][half][cg*4 + 0] = (float)c0;
      cnt_s[t][half][cg*4 + 1] = (float)c1;
      cnt_s[t][half][cg*4 + 2] = (float)c2;
      cnt_s[t][half][cg*4 + 3] = (float)c3;
    }
  }
  __syncthreads();    // the only barrier

  if (tid < 160) {
    // logits_seq: out[20 + (t,b,o)]
    int t  = tid / (BB*OUTC);
    int r  = tid - t*(BB*OUTC);
    int bq = r / OUTC;
    int o  = r - bq*OUTC;
    float acc = bhead[o];
#pragma unroll
    for (int d = 0; d < HID; ++d)
      acc = fmaf(cnt_s[t][bq][d] * (1.0f/9216.0f), whead[d*OUTC + o], acc);
    out[20 + tid] = acc;
  } else if (tid < 180) {
    // time-mean readout, independent of logits threads
    int r  = tid - 160;
    int bq = r / OUTC;
    int o  = r - bq*OUTC;
    float acc = bhead[o];
#pragma unroll
    for (int d = 0; d < HID; ++d) {
      float s = 0.f;
#pragma unroll
      for (int t = 0; t < TT; ++t) s += cnt_s[t][bq][d];
      acc = fmaf(s * (1.0f/(9216.0f*TT)), whead[d*OUTC + o], acc);
    }
    out[r] = acc;
  } else if (tid >= 192 && tid < 256) {
    // sr: one wave reduces all 256 counts (exact integers in fp32, any order)
    int i = tid - 192;
    const float* cf = &cnt_s[0][0][0];
    float s = cf[i] + cf[i + 64] + cf[i + 128] + cf[i + 192];
#pragma unroll
    for (int off = 1; off < 64; off <<= 1)
      s += __shfl_xor(s, off);
    if (i == 0) out[180] = s / DENOM;
  } else if (tid >= 256) {
    // smooth: butterfly on the preloaded partial sums
#pragma unroll
    for (int off = 1; off < 64; off <<= 1)
      smacc += __shfl_xor(smacc, off);
    if (tid == 256) out[181] = smacc / DENOM;
  }
}

extern "C" void kernel_launch(void* const* d_in, const int* in_sizes, int n_in,
                              void* d_out, int out_size, void* d_ws, size_t ws_size,
                              hipStream_t stream)
{
  const float* x     = (const float*)d_in[0];
  const float* wproj = (const float*)d_in[1];
  const float* bproj = (const float*)d_in[2];
  const float* whead = (const float*)d_in[3];
  const float* bhead = (const float*)d_in[4];
  float* out = (float*)d_out;
  float* ws  = (float*)d_ws;

  dim3 grid(HH, BB);
  snn_main<<<grid, dim3(THREADS), 0, stream>>>(x, wproj, bproj, ws);
  snn_final<<<1, dim3(320), 0, stream>>>(ws, whead, bhead, out);
}